// Round 1
// baseline (474.407 us; speedup 1.0000x reference)
//
#include <hip/hip_runtime.h>

// Problem constants (match reference)
#define BB    32
#define HH    224
#define WW    224
#define OUTC  64
#define KK    5
#define PADP  2
#define LL    (HH * WW)            // 50176 = 196 * 256

__global__ __launch_bounds__(256) void gray_conv_kernel(
    const float* __restrict__ x,     // [B, 1, H, W]
    const float* __restrict__ wgt,   // [OUT, 25]
    float* __restrict__ out)         // [B, OUT, H, W]
{
    // Weights staged in LDS. Row stride 28 floats = 112 B (multiple of 16 B)
    // so each row is 16B-aligned -> ds_read_b128-friendly. All lanes read the
    // same address per iteration -> LDS broadcast, zero bank conflicts.
    __shared__ float sw[OUTC][28];
    __shared__ float sw2[OUTC];

    const int tid = threadIdx.x;

    for (int i = tid; i < OUTC * 25; i += 256) {
        sw[i / 25][i % 25] = wgt[i];
    }
    __syncthreads();
    if (tid < OUTC) {
        float s = 0.f;
        #pragma unroll
        for (int d = 0; d < 25; ++d) { float v = sw[tid][d]; s = fmaf(v, v, s); }
        sw2[tid] = s;
    }
    __syncthreads();

    // 256 consecutive positions per block; L % 256 == 0 so each block lies in
    // exactly one batch image and stores are fully coalesced.
    const int pos = blockIdx.x * 256 + tid;     // 0 .. B*L-1
    const int b   = pos / LL;
    const int rem = pos - b * LL;
    const int h   = rem / WW;
    const int w   = rem - h * WW;

    const float* xb = x + (size_t)b * LL;

    // Load 5x5 patch (zero padding) into registers, branchless:
    // clamp the address into bounds (always-valid load), then mask to 0.
    float p[25];
    float x2 = 0.f;
    #pragma unroll
    for (int ky = 0; ky < KK; ++ky) {
        const int  yy  = h + ky - PADP;
        const int  yc  = min(max(yy, 0), HH - 1);
        const bool oky = (unsigned)yy < (unsigned)HH;
        #pragma unroll
        for (int kx = 0; kx < KK; ++kx) {
            const int  xx = w + kx - PADP;
            const int  xc = min(max(xx, 0), WW - 1);
            const bool ok = oky && ((unsigned)xx < (unsigned)WW);
            float v = xb[yc * WW + xc];
            v = ok ? v : 0.f;
            p[ky * KK + kx] = v;
            x2 = fmaf(v, v, x2);
        }
    }

    float* ob = out + (size_t)b * OUTC * LL + rem;
    #pragma unroll 4
    for (int o = 0; o < OUTC; ++o) {
        float dot = 0.f;
        #pragma unroll
        for (int d = 0; d < 25; ++d) dot = fmaf(p[d], sw[o][d], dot);
        // same formulation as reference: d2 = max(x2 + w2 - 2*x.w, 0)
        float d2 = fmaf(-2.f, dot, x2 + sw2[o]);
        d2 = fmaxf(d2, 0.f);
        ob[(size_t)o * LL] = sqrtf(d2);
    }
}

extern "C" void kernel_launch(void* const* d_in, const int* in_sizes, int n_in,
                              void* d_out, int out_size, void* d_ws, size_t ws_size,
                              hipStream_t stream) {
    const float* x   = (const float*)d_in[0];
    const float* wgt = (const float*)d_in[1];
    float* out       = (float*)d_out;

    const int total  = BB * LL;                 // 1,605,632 positions
    const int blocks = total / 256;             // 6272 blocks
    gray_conv_kernel<<<dim3(blocks), dim3(256), 0, stream>>>(x, wgt, out);
}